// Round 4
// baseline (1328.123 us; speedup 1.0000x reference)
//
#include <hip/hip_runtime.h>
#include <hip/hip_bf16.h>
#include <math.h>

// Problem constants
#define B_ 2
#define S_ 2048
#define D_ 4096
#define H_ 32
#define G_ 8
#define HD_ 128
#define GROUP_ 4
#define SCALE_ 0.08838834764831845f

typedef short bfv8 __attribute__((ext_vector_type(8)));   // 8 bf16 (4 VGPRs)
typedef float f32x4 __attribute__((ext_vector_type(4)));

__device__ __forceinline__ f32x4 mfma16(bfv8 a, bfv8 b, f32x4 c) {
  return __builtin_amdgcn_mfma_f32_16x16x32_bf16(a, b, c, 0, 0, 0);
}

__device__ __forceinline__ ushort f2bf_bits(float f) {
  __hip_bfloat16 h = __float2bfloat16(f);
  return *reinterpret_cast<ushort*>(&h);
}

// ---------------- f32 -> bf16 elementwise convert (x) ----------------
__global__ __launch_bounds__(256) void k_cvt(const float* __restrict__ in,
                                             ushort* __restrict__ out, int n4) {
  int i = blockIdx.x * 256 + threadIdx.x;
  if (i >= n4) return;
  float4 v = *(const float4*)(in + (size_t)i * 4);
  ushort4 o;
  o.x = f2bf_bits(v.x); o.y = f2bf_bits(v.y); o.z = f2bf_bits(v.z); o.w = f2bf_bits(v.w);
  *(ushort4*)(out + (size_t)i * 4) = o;
}

// ---------------- transpose (R x C) f32 -> (C x R) bf16 ----------------
__global__ __launch_bounds__(256) void k_transpose(const float* __restrict__ in,
                                                   ushort* __restrict__ out,
                                                   int R, int C) {
  __shared__ ushort tile[32][33];
  int bc = blockIdx.x * 32;
  int br = blockIdx.y * 32;
  int tx = threadIdx.x;   // 0..31
  int ty = threadIdx.y;   // 0..7
  for (int ii = 0; ii < 4; ii++) {
    int i = ty + ii * 8;
    tile[i][tx] = f2bf_bits(in[(size_t)(br + i) * C + bc + tx]);
  }
  __syncthreads();
  for (int ii = 0; ii < 4; ii++) {
    int i = ty + ii * 8;
    out[(size_t)(bc + i) * R + br + tx] = tile[tx][i];
  }
}

// V (B,S,G,HD) bf16 -> VT (B,G,HD,S) bf16
__global__ __launch_bounds__(256) void k_transpose_v(const ushort* __restrict__ v,
                                                     ushort* __restrict__ vt) {
  __shared__ ushort tile[32][33];
  int bg = blockIdx.z;
  int b = bg / G_, g = bg % G_;
  int s0 = blockIdx.y * 32;
  int h0 = blockIdx.x * 32;   // hd base
  int tx = threadIdx.x, ty = threadIdx.y;
  const ushort* src = v + (size_t)b * S_ * G_ * HD_ + (size_t)g * HD_;
  ushort* dst = vt + (size_t)(b * G_ + g) * HD_ * S_;
  for (int ii = 0; ii < 4; ii++) {
    int i = ty + ii * 8;
    tile[i][tx] = src[(size_t)(s0 + i) * (G_ * HD_) + h0 + tx];
  }
  __syncthreads();
  for (int ii = 0; ii < 4; ii++) {
    int i = ty + ii * 8;
    dst[(size_t)(h0 + i) * S_ + s0 + tx] = tile[tx][i];
  }
}

// ---------------- RoPE (in-place, bf16 t; f32 cos/sin) ----------------
__global__ __launch_bounds__(64) void k_rope(__hip_bfloat16* __restrict__ t,
                                             const float* __restrict__ cosb,
                                             const float* __restrict__ sinb,
                                             int nheads, float scale) {
  int blk = blockIdx.x;
  int head = blk % nheads;
  int row = blk / nheads;        // b*S + s
  int s = row & (S_ - 1);
  int l = threadIdx.x;           // 0..63
  size_t base = (size_t)row * nheads * HD_ + (size_t)head * HD_;
  float x1 = __bfloat162float(t[base + l]);
  float x2 = __bfloat162float(t[base + 64 + l]);
  float c1 = cosb[s * HD_ + l];
  float sn1 = sinb[s * HD_ + l];
  float c2 = cosb[s * HD_ + 64 + l];
  float sn2 = sinb[s * HD_ + 64 + l];
  t[base + l] = __float2bfloat16((x1 * c1 - x2 * sn1) * scale);
  t[base + 64 + l] = __float2bfloat16((x2 * c2 + x1 * sn2) * scale);
}

// ---------------- GEMM: C(M,N) = A(M,K) @ B(K,N) with B given as BT(N,K) -----
// A,BT bf16; C templated (bf16 intermediate / f32 final output).
// 128x128 tile, BK=32, 256 threads = 4 waves (2x2), each wave 64x64 (4x4 frags)
template <typename OT>
__global__ __launch_bounds__(256) void k_gemm_bt(const __hip_bfloat16* __restrict__ Ab,
                                                 const __hip_bfloat16* __restrict__ BTb,
                                                 OT* __restrict__ Cb,
                                                 int M, int N, int K) {
  __shared__ short sA[128 * 32];
  __shared__ short sB[128 * 32];
  int t = threadIdx.x;
  int w = t >> 6;
  int l = t & 63;
  int row0 = blockIdx.y * 128;
  int col0 = blockIdx.x * 128;
  int wr = (w >> 1) * 64;
  int wc = (w & 1) * 64;
  int lr = t >> 2;          // 0..63
  int lc = (t & 3) * 8;     // 0,8,16,24
  int fr = l & 15;
  int fq = l >> 4;
  int fo = fq * 8;

  const short* gA = (const short*)Ab;
  const short* gB = (const short*)BTb;

  f32x4 acc[4][4];
#pragma unroll
  for (int m = 0; m < 4; m++)
#pragma unroll
    for (int n = 0; n < 4; n++) acc[m][n] = (f32x4){0.f, 0.f, 0.f, 0.f};

  for (int k0 = 0; k0 < K; k0 += 32) {
    bfv8 ra0 = *(const bfv8*)(gA + (size_t)(row0 + lr) * K + k0 + lc);
    bfv8 ra1 = *(const bfv8*)(gA + (size_t)(row0 + 64 + lr) * K + k0 + lc);
    bfv8 rb0 = *(const bfv8*)(gB + (size_t)(col0 + lr) * K + k0 + lc);
    bfv8 rb1 = *(const bfv8*)(gB + (size_t)(col0 + 64 + lr) * K + k0 + lc);
    __syncthreads();
    *(bfv8*)(sA + lr * 32 + lc) = ra0;
    *(bfv8*)(sA + (64 + lr) * 32 + lc) = ra1;
    *(bfv8*)(sB + lr * 32 + lc) = rb0;
    *(bfv8*)(sB + (64 + lr) * 32 + lc) = rb1;
    __syncthreads();
    bfv8 af[4], bff[4];
#pragma unroll
    for (int m = 0; m < 4; m++) af[m] = *(const bfv8*)(sA + (wr + m * 16 + fr) * 32 + fo);
#pragma unroll
    for (int n = 0; n < 4; n++) bff[n] = *(const bfv8*)(sB + (wc + n * 16 + fr) * 32 + fo);
#pragma unroll
    for (int m = 0; m < 4; m++)
#pragma unroll
      for (int n = 0; n < 4; n++)
        acc[m][n] = mfma16(af[m], bff[n], acc[m][n]);
  }
#pragma unroll
  for (int m = 0; m < 4; m++)
#pragma unroll
    for (int n = 0; n < 4; n++)
#pragma unroll
      for (int j = 0; j < 4; j++) {
        int r = row0 + wr + m * 16 + fq * 4 + j;
        int c = col0 + wc + n * 16 + fr;
        if constexpr (__is_same(OT, float)) {
          Cb[(size_t)r * N + c] = acc[m][n][j];
        } else {
          Cb[(size_t)r * N + c] = __float2bfloat16(acc[m][n][j]);
        }
      }
}

// ---------------- flash attention: 1 wave per (b,h,16 q-rows) ----------------
// Q: (B,S,H,HD) roped+scaled; K: (B,S,G,HD) roped; VT: (B,G,HD,S); ctx: (B,S,H,HD)
__global__ __launch_bounds__(64) void k_attn(const __hip_bfloat16* __restrict__ Qb,
                                             const __hip_bfloat16* __restrict__ Kb,
                                             const __hip_bfloat16* __restrict__ VTb,
                                             __hip_bfloat16* __restrict__ ctx) {
  __shared__ ushort sP[16 * 32];
  const int QT = S_ / 16;
  int blk = blockIdx.x;
  int qt = blk % QT;
  int bh = blk / QT;
  int h = bh % H_;
  int b = bh / H_;
  int g = h / GROUP_;
  int q0 = qt * 16;
  int l = threadIdx.x;
  int fr = l & 15;
  int fq = l >> 4;
  int fo = fq * 8;

  const short* qp = (const short*)Qb + (size_t)b * S_ * H_ * HD_ + (size_t)h * HD_;
  const short* kp = (const short*)Kb + (size_t)b * S_ * G_ * HD_ + (size_t)g * HD_;
  const short* vp = (const short*)VTb + (size_t)(b * G_ + g) * HD_ * S_;

  bfv8 qf[4];
#pragma unroll
  for (int c = 0; c < 4; c++)
    qf[c] = *(const bfv8*)(qp + (size_t)(q0 + fr) * (H_ * HD_) + c * 32 + fo);

  f32x4 acc[8];
#pragma unroll
  for (int n = 0; n < 8; n++) acc[n] = (f32x4){0.f, 0.f, 0.f, 0.f};
  float m[4], ll[4];
#pragma unroll
  for (int j = 0; j < 4; j++) { m[j] = -INFINITY; ll[j] = 0.f; }

  int nkt = q0 / 32 + 1;   // k0 = kt*32 <= q0 always; covers all k <= q0+15
  for (int kt = 0; kt < nkt; kt++) {
    int k0 = kt * 32;
    f32x4 s0 = (f32x4){0.f, 0.f, 0.f, 0.f};
    f32x4 s1 = (f32x4){0.f, 0.f, 0.f, 0.f};
#pragma unroll
    for (int c = 0; c < 4; c++) {
      bfv8 kf0 = *(const bfv8*)(kp + (size_t)(k0 + fr) * (G_ * HD_) + c * 32 + fo);
      bfv8 kf1 = *(const bfv8*)(kp + (size_t)(k0 + 16 + fr) * (G_ * HD_) + c * 32 + fo);
      s0 = mfma16(qf[c], kf0, s0);
      s1 = mfma16(qf[c], kf1, s1);
    }
    // causal mask + per-row (D-layout: row = fq*4+j, col = k0[+16]+fr) softmax
    float p0[4], p1[4], sc[4], red[4];
#pragma unroll
    for (int j = 0; j < 4; j++) {
      int q = q0 + fq * 4 + j;
      if (k0 + fr > q) s0[j] = -INFINITY;
      if (k0 + 16 + fr > q) s1[j] = -INFINITY;
      red[j] = fmaxf(s0[j], s1[j]);
    }
#pragma unroll
    for (int off = 1; off < 16; off <<= 1)
#pragma unroll
      for (int j = 0; j < 4; j++)
        red[j] = fmaxf(red[j], __shfl_xor(red[j], off, 64));
#pragma unroll
    for (int j = 0; j < 4; j++) {
      float nm = fmaxf(m[j], red[j]);
      sc[j] = __expf(m[j] - nm);
      m[j] = nm;
      p0[j] = __expf(s0[j] - nm);
      p1[j] = __expf(s1[j] - nm);
      red[j] = p0[j] + p1[j];
    }
#pragma unroll
    for (int off = 1; off < 16; off <<= 1)
#pragma unroll
      for (int j = 0; j < 4; j++)
        red[j] += __shfl_xor(red[j], off, 64);
#pragma unroll
    for (int j = 0; j < 4; j++) {
      ll[j] = ll[j] * sc[j] + red[j];
#pragma unroll
      for (int n = 0; n < 8; n++) acc[n][j] *= sc[j];
      sP[(fq * 4 + j) * 32 + fr] = f2bf_bits(p0[j]);
      sP[(fq * 4 + j) * 32 + 16 + fr] = f2bf_bits(p1[j]);
    }
    __syncthreads();
    bfv8 pa = *(const bfv8*)((const short*)sP + fr * 32 + fo);
#pragma unroll
    for (int n = 0; n < 8; n++) {
      bfv8 vf = *(const bfv8*)(vp + (size_t)(n * 16 + fr) * S_ + k0 + fo);
      acc[n] = mfma16(pa, vf, acc[n]);
    }
    __syncthreads();
  }
#pragma unroll
  for (int n = 0; n < 8; n++)
#pragma unroll
    for (int j = 0; j < 4; j++) {
      int q = q0 + fq * 4 + j;
      float o = acc[n][j] / ll[j];
      ctx[(size_t)(b * S_ + q) * (H_ * HD_) + h * HD_ + n * 16 + fr] = __float2bfloat16(o);
    }
}

extern "C" void kernel_launch(void* const* d_in, const int* in_sizes, int n_in,
                              void* d_out, int out_size, void* d_ws, size_t ws_size,
                              hipStream_t stream) {
  (void)in_sizes; (void)n_in; (void)out_size; (void)ws_size;
  // Reference dtypes are float32 -> all inputs are f32, output is f32.
  const float* x    = (const float*)d_in[0];
  const float* Wq   = (const float*)d_in[1];
  const float* Wk   = (const float*)d_in[2];
  const float* Wv   = (const float*)d_in[3];
  const float* Wo   = (const float*)d_in[4];
  const float* cosb = (const float*)d_in[5];
  const float* sinb = (const float*)d_in[6];
  // d_in[7] = mask (fixed causal triu), d_in[8] = start_pos (0) — implemented directly.

  // ws layout (bytes); total 142.6 MB.
  // Cx aliases xb (x dead after V-proj). WoT aliases WqT (dead after Q-proj).
  char* ws = (char*)d_ws;
  __hip_bfloat16* xb  = (__hip_bfloat16*)(ws + 0);           // (B,S,D) bf16, later Cx
  __hip_bfloat16* WqT = (__hip_bfloat16*)(ws + 33554432);    // 4096x4096, later WoT
  __hip_bfloat16* WkT = (__hip_bfloat16*)(ws + 67108864);    // 1024x4096
  __hip_bfloat16* WvT = (__hip_bfloat16*)(ws + 75497472);    // 1024x4096
  __hip_bfloat16* Qb  = (__hip_bfloat16*)(ws + 83886080);    // (B,S,H,HD)
  __hip_bfloat16* Kb  = (__hip_bfloat16*)(ws + 117440512);   // (B,S,G,HD)
  __hip_bfloat16* Vb  = (__hip_bfloat16*)(ws + 125829120);   // (B,S,G,HD)
  __hip_bfloat16* VTb = (__hip_bfloat16*)(ws + 134217728);   // (B,G,HD,S)
  __hip_bfloat16* Cx  = xb;                                  // alias

  dim3 tb(32, 8);
  // x -> bf16
  k_cvt<<<(B_ * S_ * D_ / 4 + 255) / 256, 256, 0, stream>>>(x, (ushort*)xb, B_ * S_ * D_ / 4);
  // weight transposes+convert (K-contiguous B^T layout for the GEMMs)
  k_transpose<<<dim3(128, 128), tb, 0, stream>>>(Wq, (ushort*)WqT, 4096, 4096);
  k_transpose<<<dim3(32, 128), tb, 0, stream>>>(Wk, (ushort*)WkT, 4096, 1024);
  k_transpose<<<dim3(32, 128), tb, 0, stream>>>(Wv, (ushort*)WvT, 4096, 1024);

  // projections (bf16 out)
  k_gemm_bt<__hip_bfloat16><<<dim3(32, 32), 256, 0, stream>>>(xb, WqT, Qb, 4096, 4096, 4096);
  k_gemm_bt<__hip_bfloat16><<<dim3(8, 32), 256, 0, stream>>>(xb, WkT, Kb, 4096, 1024, 4096);
  k_gemm_bt<__hip_bfloat16><<<dim3(8, 32), 256, 0, stream>>>(xb, WvT, Vb, 4096, 1024, 4096);

  // WqT region is free now — put WoT there
  k_transpose<<<dim3(128, 128), tb, 0, stream>>>(Wo, (ushort*)WqT, 4096, 4096);

  // RoPE (+scale on Q)
  k_rope<<<4096 * 32, 64, 0, stream>>>(Qb, cosb, sinb, 32, SCALE_);
  k_rope<<<4096 * 8, 64, 0, stream>>>(Kb, cosb, sinb, 8, 1.0f);

  // V -> VT for contiguous PV B-fragments
  k_transpose_v<<<dim3(4, 64, 16), tb, 0, stream>>>((const ushort*)Vb, (ushort*)VTb);

  // causal GQA flash attention (writes Cx = xb region; x is dead by now)
  k_attn<<<B_ * H_ * (S_ / 16), 64, 0, stream>>>(Qb, Kb, VTb, Cx);

  // output projection straight into d_out (f32)
  k_gemm_bt<float><<<dim3(32, 32), 256, 0, stream>>>(Cx, WqT, (float*)d_out, 4096, 4096, 4096);
}

// Round 9
// 955.972 us; speedup vs baseline: 1.3893x; 1.3893x over previous
//
#include <hip/hip_runtime.h>
#include <hip/hip_bf16.h>
#include <math.h>

// Problem constants
#define B_ 2
#define S_ 2048
#define D_ 4096
#define H_ 32
#define G_ 8
#define HD_ 128
#define GROUP_ 4
#define SCALE_ 0.08838834764831845f

typedef short bfv8 __attribute__((ext_vector_type(8)));   // 8 bf16 (4 VGPRs)
typedef float f32x4 __attribute__((ext_vector_type(4)));

__device__ __forceinline__ f32x4 mfma16(bfv8 a, bfv8 b, f32x4 c) {
  return __builtin_amdgcn_mfma_f32_16x16x32_bf16(a, b, c, 0, 0, 0);
}

__device__ __forceinline__ ushort f2bf_bits(float f) {
  __hip_bfloat16 h = __float2bfloat16(f);
  return *reinterpret_cast<ushort*>(&h);
}

// async global->LDS, 16B per lane; LDS dest = wave-uniform base + lane*16 (HW);
// global src is per-lane (enables source-side swizzle per rule #21).
__device__ __forceinline__ void gload16(const short* g, short* l) {
  __builtin_amdgcn_global_load_lds(
      (const __attribute__((address_space(1))) void*)g,
      (__attribute__((address_space(3))) void*)l, 16, 0, 0);
}

// ---------------- f32 -> bf16 elementwise convert (x) ----------------
__global__ __launch_bounds__(256) void k_cvt(const float* __restrict__ in,
                                             ushort* __restrict__ out, int n4) {
  int i = blockIdx.x * 256 + threadIdx.x;
  if (i >= n4) return;
  float4 v = *(const float4*)(in + (size_t)i * 4);
  ushort4 o;
  o.x = f2bf_bits(v.x); o.y = f2bf_bits(v.y); o.z = f2bf_bits(v.z); o.w = f2bf_bits(v.w);
  *(ushort4*)(out + (size_t)i * 4) = o;
}

// ---------------- transpose (R x C) f32 -> (C x R) bf16 ----------------
__global__ __launch_bounds__(256) void k_transpose(const float* __restrict__ in,
                                                   ushort* __restrict__ out,
                                                   int R, int C) {
  __shared__ ushort tile[32][33];
  int bc = blockIdx.x * 32;
  int br = blockIdx.y * 32;
  int tx = threadIdx.x;   // 0..31
  int ty = threadIdx.y;   // 0..7
  for (int ii = 0; ii < 4; ii++) {
    int i = ty + ii * 8;
    tile[i][tx] = f2bf_bits(in[(size_t)(br + i) * C + bc + tx]);
  }
  __syncthreads();
  for (int ii = 0; ii < 4; ii++) {
    int i = ty + ii * 8;
    out[(size_t)(bc + i) * R + br + tx] = tile[tx][i];
  }
}

// V (B,S,G,HD) bf16 -> VT (B,G,HD,S) bf16
__global__ __launch_bounds__(256) void k_transpose_v(const ushort* __restrict__ v,
                                                     ushort* __restrict__ vt) {
  __shared__ ushort tile[32][33];
  int bg = blockIdx.z;
  int b = bg / G_, g = bg % G_;
  int s0 = blockIdx.y * 32;
  int h0 = blockIdx.x * 32;   // hd base
  int tx = threadIdx.x, ty = threadIdx.y;
  const ushort* src = v + (size_t)b * S_ * G_ * HD_ + (size_t)g * HD_;
  ushort* dst = vt + (size_t)(b * G_ + g) * HD_ * S_;
  for (int ii = 0; ii < 4; ii++) {
    int i = ty + ii * 8;
    tile[i][tx] = src[(size_t)(s0 + i) * (G_ * HD_) + h0 + tx];
  }
  __syncthreads();
  for (int ii = 0; ii < 4; ii++) {
    int i = ty + ii * 8;
    dst[(size_t)(h0 + i) * S_ + s0 + tx] = tile[tx][i];
  }
}

// ---------------- RoPE (in-place, bf16 t; f32 cos/sin) ----------------
__global__ __launch_bounds__(64) void k_rope(__hip_bfloat16* __restrict__ t,
                                             const float* __restrict__ cosb,
                                             const float* __restrict__ sinb,
                                             int nheads, float scale) {
  int blk = blockIdx.x;
  int head = blk % nheads;
  int row = blk / nheads;        // b*S + s
  int s = row & (S_ - 1);
  int l = threadIdx.x;           // 0..63
  size_t base = (size_t)row * nheads * HD_ + (size_t)head * HD_;
  float x1 = __bfloat162float(t[base + l]);
  float x2 = __bfloat162float(t[base + 64 + l]);
  float c1 = cosb[s * HD_ + l];
  float sn1 = sinb[s * HD_ + l];
  float c2 = cosb[s * HD_ + 64 + l];
  float sn2 = sinb[s * HD_ + 64 + l];
  t[base + l] = __float2bfloat16((x1 * c1 - x2 * sn1) * scale);
  t[base + 64 + l] = __float2bfloat16((x2 * c2 + x1 * sn2) * scale);
}

// ---------------- GEMM: C(M,N) = A(M,K) @ B(K,N) with B given as BT(N,K) -----
// m97 structure: 128x128 tile, BK=32, 4 waves, global_load_lds width-16 staging.
template <typename OT>
__global__ __launch_bounds__(256) void k_gemm_bt(const __hip_bfloat16* __restrict__ Ab,
                                                 const __hip_bfloat16* __restrict__ BTb,
                                                 OT* __restrict__ Cb,
                                                 int M, int N, int K) {
  __shared__ short sA[128 * 32];
  __shared__ short sB[128 * 32];
  int t = threadIdx.x;
  int w = t >> 6;
  int l = t & 63;
  int row0 = blockIdx.y * 128;
  int col0 = blockIdx.x * 128;
  int wr = (w >> 1) * 64;
  int wc = (w & 1) * 64;
  int fr = l & 15;
  int fq = l >> 4;
  int fo = fq * 8;
  int srow = l >> 2;        // 0..15 staging row within 16-row group
  int schk = (l & 3) * 8;   // staging chunk (elements)

  const short* gA = (const short*)Ab;
  const short* gB = (const short*)BTb;

  f32x4 acc[4][4];
#pragma unroll
  for (int m = 0; m < 4; m++)
#pragma unroll
    for (int n = 0; n < 4; n++) acc[m][n] = (f32x4){0.f, 0.f, 0.f, 0.f};

  for (int k0 = 0; k0 < K; k0 += 32) {
    __syncthreads();   // previous iteration's LDS reads complete before overwrite
#pragma unroll
    for (int j = 0; j < 2; j++) {
      int r = w * 32 + j * 16;   // wave-uniform LDS base row
      gload16(gA + (size_t)(row0 + r + srow) * K + k0 + schk, &sA[r * 32]);
      gload16(gB + (size_t)(col0 + r + srow) * K + k0 + schk, &sB[r * 32]);
    }
    __syncthreads();   // drains vmcnt: tiles ready
    bfv8 af[4], bff[4];
#pragma unroll
    for (int m = 0; m < 4; m++) af[m] = *(const bfv8*)(sA + (wr + m * 16 + fr) * 32 + fo);
#pragma unroll
    for (int n = 0; n < 4; n++) bff[n] = *(const bfv8*)(sB + (wc + n * 16 + fr) * 32 + fo);
#pragma unroll
    for (int m = 0; m < 4; m++)
#pragma unroll
      for (int n = 0; n < 4; n++)
        acc[m][n] = mfma16(af[m], bff[n], acc[m][n]);
  }
#pragma unroll
  for (int m = 0; m < 4; m++)
#pragma unroll
    for (int n = 0; n < 4; n++)
#pragma unroll
      for (int j = 0; j < 4; j++) {
        int r = row0 + wr + m * 16 + fq * 4 + j;
        int c = col0 + wc + n * 16 + fr;
        if constexpr (__is_same(OT, float)) {
          Cb[(size_t)r * N + c] = acc[m][n][j];
        } else {
          Cb[(size_t)r * N + c] = __float2bfloat16(acc[m][n][j]);
        }
      }
}

// ---------------- flash attention v2: 8 waves/block, 128 q-rows, KVBLK=64 ----
// K-tile [64][128] and VT-tile [128][64] staged via global_load_lds with
// source-side XOR swizzle (chunk ^= row&7); swizzled ds_read_b128 on reads.
// Per wave: 16 q-rows, 16x16x32 MFMA; P via per-wave LDS (stride 68).
#define PSTR 68
__global__ __launch_bounds__(512) void k_attn2(const __hip_bfloat16* __restrict__ Qb,
                                               const __hip_bfloat16* __restrict__ Kb,
                                               const __hip_bfloat16* __restrict__ VTb,
                                               __hip_bfloat16* __restrict__ ctx) {
  __shared__ short sK[64 * 128];        // [k][d], rows 256B, 16 chunks
  __shared__ short sV[128 * 64];        // [d][k], rows 128B, 8 chunks
  __shared__ short sP[8][16 * PSTR];    // per-wave P[16 q][64 k]

  const int nQB = S_ / 128;             // 16
  int blk = blockIdx.x;
  int qb = (nQB - 1) - (blk % nQB);     // heavy blocks dispatched first
  int bh = blk / nQB;
  int h = bh % H_;
  int b = bh / H_;
  int g = h / GROUP_;
  int q0 = qb * 128;

  int t = threadIdx.x;
  int wid = t >> 6;
  int l = t & 63;
  int fr = l & 15, fq = l >> 4, fo = fq * 8;
  int wq0 = q0 + wid * 16;              // this wave's q rows

  const short* qp = (const short*)Qb + (size_t)b * S_ * H_ * HD_ + (size_t)h * HD_;
  const short* kp = (const short*)Kb + (size_t)b * S_ * G_ * HD_ + (size_t)g * HD_;
  const short* vp = (const short*)VTb + (size_t)(b * G_ + g) * HD_ * S_;

  bfv8 qf[4];
#pragma unroll
  for (int c = 0; c < 4; c++)
    qf[c] = *(const bfv8*)(qp + (size_t)(wq0 + fr) * (H_ * HD_) + c * 32 + fo);

  f32x4 acc[8];
#pragma unroll
  for (int n = 0; n < 8; n++) acc[n] = (f32x4){0.f, 0.f, 0.f, 0.f};
  float m[4], ll[4];
#pragma unroll
  for (int j = 0; j < 4; j++) { m[j] = -INFINITY; ll[j] = 0.f; }

  // staging lane decomposition
  int krow_i = l >> 4;   // K: 4 rows per issue
  int kchk = l & 15;     // K chunk 0..15
  int vrow_i = l >> 3;   // V: 8 rows per issue
  int vchk = l & 7;      // V chunk 0..7

  int nkt = 2 * qb + 2;  // 64-k tiles covering k <= q0+127
  for (int kt = 0; kt < nkt; kt++) {
    int k0 = kt * 64;
    // ---- cooperative staging: K 8 rows/wave (2 issues), V 16 rows/wave (2 issues)
#pragma unroll
    for (int j = 0; j < 2; j++) {
      int base = wid * 8 + j * 4;              // wave-uniform
      int r = base + krow_i;                   // per-lane LDS row it fills
      gload16(kp + (size_t)(k0 + r) * (G_ * HD_) + ((kchk ^ (r & 7)) * 8), &sK[base * 128]);
    }
#pragma unroll
    for (int j = 0; j < 2; j++) {
      int base = wid * 16 + j * 8;
      int r = base + vrow_i;                   // d-row
      gload16(vp + (size_t)r * S_ + k0 + ((vchk ^ (r & 7)) * 8), &sV[base * 64]);
    }
    __syncthreads();   // vmcnt drained by barrier: K/V tiles ready

    // ---- QK^T over 64 k (4 sub-tiles of 16)
    f32x4 sf[4];
#pragma unroll
    for (int ks = 0; ks < 4; ks++) {
      sf[ks] = (f32x4){0.f, 0.f, 0.f, 0.f};
      int row = ks * 16 + fr;
      int rx = row & 7;
#pragma unroll
      for (int c = 0; c < 4; c++) {
        bfv8 kf = *(const bfv8*)&sK[row * 128 + (((c * 4 + fq) ^ rx) * 8)];
        sf[ks] = mfma16(qf[c], kf, sf[ks]);
      }
    }

    // ---- causal mask + online softmax (rows = fq*4+j, cols = ks*16+fr)
    float p[4][4], sc[4], red[4];
#pragma unroll
    for (int j = 0; j < 4; j++) {
      int q = wq0 + fq * 4 + j;
#pragma unroll
      for (int ks = 0; ks < 4; ks++)
        if (k0 + ks * 16 + fr > q) sf[ks][j] = -INFINITY;
      red[j] = fmaxf(fmaxf(sf[0][j], sf[1][j]), fmaxf(sf[2][j], sf[3][j]));
    }
#pragma unroll
    for (int off = 1; off < 16; off <<= 1)
#pragma unroll
      for (int j = 0; j < 4; j++)
        red[j] = fmaxf(red[j], __shfl_xor(red[j], off, 64));
#pragma unroll
    for (int j = 0; j < 4; j++) {
      float nm = fmaxf(m[j], red[j]);
      sc[j] = __expf(m[j] - nm);
      m[j] = nm;
#pragma unroll
      for (int ks = 0; ks < 4; ks++) p[ks][j] = __expf(sf[ks][j] - nm);
      red[j] = (p[0][j] + p[1][j]) + (p[2][j] + p[3][j]);
    }
#pragma unroll
    for (int off = 1; off < 16; off <<= 1)
#pragma unroll
      for (int j = 0; j < 4; j++)
        red[j] += __shfl_xor(red[j], off, 64);
#pragma unroll
    for (int j = 0; j < 4; j++) {
      ll[j] = ll[j] * sc[j] + red[j];
#pragma unroll
      for (int n = 0; n < 8; n++) acc[n][j] *= sc[j];
#pragma unroll
      for (int ks = 0; ks < 4; ks++)
        sP[wid][(fq * 4 + j) * PSTR + ks * 16 + fr] = f2bf_bits(p[ks][j]);
    }

    // ---- PV: O += P[16x64] @ V[64x128]  (own-wave sP; lgkm ordering in-wave)
    bfv8 pa0 = *(const bfv8*)&sP[wid][fr * PSTR + fo];
    bfv8 pa1 = *(const bfv8*)&sP[wid][fr * PSTR + 32 + fo];
#pragma unroll
    for (int n = 0; n < 8; n++) {
      int row = n * 16 + fr;
      int rx = row & 7;
      bfv8 vf0 = *(const bfv8*)&sV[row * 64 + ((fq ^ rx) * 8)];
      bfv8 vf1 = *(const bfv8*)&sV[row * 64 + (((4 + fq) ^ rx) * 8)];
      acc[n] = mfma16(pa0, vf0, acc[n]);
      acc[n] = mfma16(pa1, vf1, acc[n]);
    }
    __syncthreads();   // all waves done reading before next tile's staging
  }

#pragma unroll
  for (int n = 0; n < 8; n++)
#pragma unroll
    for (int j = 0; j < 4; j++) {
      int q = wq0 + fq * 4 + j;
      float o = acc[n][j] / ll[j];
      ctx[(size_t)(b * S_ + q) * (H_ * HD_) + h * HD_ + n * 16 + fr] = __float2bfloat16(o);
    }
}

extern "C" void kernel_launch(void* const* d_in, const int* in_sizes, int n_in,
                              void* d_out, int out_size, void* d_ws, size_t ws_size,
                              hipStream_t stream) {
  (void)in_sizes; (void)n_in; (void)out_size; (void)ws_size;
  // Reference dtypes are float32 -> all inputs are f32, output is f32.
  const float* x    = (const float*)d_in[0];
  const float* Wq   = (const float*)d_in[1];
  const float* Wk   = (const float*)d_in[2];
  const float* Wv   = (const float*)d_in[3];
  const float* Wo   = (const float*)d_in[4];
  const float* cosb = (const float*)d_in[5];
  const float* sinb = (const float*)d_in[6];
  // d_in[7] = mask (fixed causal triu), d_in[8] = start_pos (0) — implemented directly.

  // ws layout (bytes); total 142.6 MB.
  // Cx aliases xb (x dead after V-proj). WoT aliases WqT (dead after Q-proj).
  char* ws = (char*)d_ws;
  __hip_bfloat16* xb  = (__hip_bfloat16*)(ws + 0);           // (B,S,D) bf16, later Cx
  __hip_bfloat16* WqT = (__hip_bfloat16*)(ws + 33554432);    // 4096x4096, later WoT
  __hip_bfloat16* WkT = (__hip_bfloat16*)(ws + 67108864);    // 1024x4096
  __hip_bfloat16* WvT = (__hip_bfloat16*)(ws + 75497472);    // 1024x4096
  __hip_bfloat16* Qb  = (__hip_bfloat16*)(ws + 83886080);    // (B,S,H,HD)
  __hip_bfloat16* Kb  = (__hip_bfloat16*)(ws + 117440512);   // (B,S,G,HD)
  __hip_bfloat16* Vb  = (__hip_bfloat16*)(ws + 125829120);   // (B,S,G,HD)
  __hip_bfloat16* VTb = (__hip_bfloat16*)(ws + 134217728);   // (B,G,HD,S)
  __hip_bfloat16* Cx  = xb;                                  // alias

  dim3 tb(32, 8);
  // x -> bf16
  k_cvt<<<(B_ * S_ * D_ / 4 + 255) / 256, 256, 0, stream>>>(x, (ushort*)xb, B_ * S_ * D_ / 4);
  // weight transposes+convert (K-contiguous B^T layout for the GEMMs)
  k_transpose<<<dim3(128, 128), tb, 0, stream>>>(Wq, (ushort*)WqT, 4096, 4096);
  k_transpose<<<dim3(32, 128), tb, 0, stream>>>(Wk, (ushort*)WkT, 4096, 1024);
  k_transpose<<<dim3(32, 128), tb, 0, stream>>>(Wv, (ushort*)WvT, 4096, 1024);

  // projections (bf16 out)
  k_gemm_bt<__hip_bfloat16><<<dim3(32, 32), 256, 0, stream>>>(xb, WqT, Qb, 4096, 4096, 4096);
  k_gemm_bt<__hip_bfloat16><<<dim3(8, 32), 256, 0, stream>>>(xb, WkT, Kb, 4096, 1024, 4096);
  k_gemm_bt<__hip_bfloat16><<<dim3(8, 32), 256, 0, stream>>>(xb, WvT, Vb, 4096, 1024, 4096);

  // WqT region is free now — put WoT there
  k_transpose<<<dim3(128, 128), tb, 0, stream>>>(Wo, (ushort*)WqT, 4096, 4096);

  // RoPE (+scale on Q)
  k_rope<<<4096 * 32, 64, 0, stream>>>(Qb, cosb, sinb, 32, SCALE_);
  k_rope<<<4096 * 8, 64, 0, stream>>>(Kb, cosb, sinb, 8, 1.0f);

  // V -> VT for contiguous PV B-fragments
  k_transpose_v<<<dim3(4, 64, 16), tb, 0, stream>>>((const ushort*)Vb, (ushort*)VTb);

  // causal GQA flash attention v2 (writes Cx = xb region; x is dead by now)
  k_attn2<<<B_ * H_ * (S_ / 128), 512, 0, stream>>>(Qb, Kb, VTb, Cx);

  // output projection straight into d_out (f32)
  k_gemm_bt<float><<<dim3(32, 32), 256, 0, stream>>>(Cx, WqT, (float*)d_out, 4096, 4096, 4096);
}